// Round 4
// baseline (109.737 us; speedup 1.0000x reference)
//
#include <hip/hip_runtime.h>
#include <math.h>

// GMM score, rescaled: out_j = (E_w[td] - x_j) / sigma2_j
// w_i = exp(-0.5 (td_i - x_j)^2 / sigma2_j), sigma2_j = (exp(2 t_j ln25)-1)/(2 ln25)
//
// B = N = 16384, d = 1. Trans/issue-bound: 268M v_exp_f32 evals.
// R4 changes vs R3 (which was ~2x above its issue floor from LDS/ILP stalls):
//  - NO LDS: the inner i-index is wave-uniform, so td[base+i] lowers to
//    s_load_dwordx8 (scalar cache); td values live in SGPRs and feed v_pk_fma
//    as the scalar operand. Kills ds_read issue slots, lgkm stall clusters,
//    the staging loop and the barrier.
//  - 2 j's per thread: 16 independent exp chains in flight (was 8); each
//    scalar td load feeds two outputs. CH=256, S=64 keeps grid at 2048 blocks
//    (8 blocks/CU = 32 waves/CU = max occupancy).
//  - instruction mix unchanged at the minimum: 2 pk-VALU + 1 exp per (i,j).

typedef float v2f __attribute__((ext_vector_type(2)));
typedef float v8f __attribute__((ext_vector_type(8)));

#define BLK 256
#define CH  256          // i's per slice
#define JPB (2 * BLK)    // j's per block (2 per thread)

#if __has_builtin(__builtin_amdgcn_exp2f)
#define EXP2(x) __builtin_amdgcn_exp2f(x)
#else
#define EXP2(x) exp2f(x)
#endif

__device__ __forceinline__ float sigma2_of(float tj) {
  const float TWO_LOG_S = 6.4377516497364011f;   // 2*ln(25)
  return (__expf(TWO_LOG_S * tj) - 1.0f) / TWO_LOG_S;
}

template <bool ATOMIC>
__launch_bounds__(BLK)
__global__ void gmm_partial(const float* __restrict__ x,
                            const float* __restrict__ t,
                            const float* __restrict__ td,
                            float* __restrict__ ws,
                            int N, int B) {
  const int tid  = threadIdx.x;
  const int j0   = blockIdx.x * JPB + tid;   // first output
  const int j1   = j0 + BLK;                 // second output (coalesced)
  const int s    = blockIdx.y;               // N-slice
  const int S    = gridDim.y;
  const int base = s * CH;
  const float* __restrict__ tp = td + base;
  const int lim = (N - base < CH) ? (N - base) : CH;   // always CH for N%CH==0

  const float HALF_LOG2E = 0.72134752044448170f;   // 0.5 * log2(e)
  float r0 = 0.f, y0 = 0.f, r1 = 0.f, y1 = 0.f;
  if (j0 < B) { r0 = __fsqrt_rn(HALF_LOG2E / sigma2_of(t[j0])); y0 = x[j0] * r0; }
  if (j1 < B) { r1 = __fsqrt_rn(HALF_LOG2E / sigma2_of(t[j1])); y1 = x[j1] * r1; }

  const v2f rv0 = {r0, r0}, ny0 = {-y0, -y0};
  const v2f rv1 = {r1, r1}, ny1 = {-y1, -y1};

  // 2 chains per accumulator per j: 16 independent exp chains in flight
  v2f nA0 = {0,0}, nB0 = {0,0}, dA0 = {0,0}, dB0 = {0,0};   // j0
  v2f nA1 = {0,0}, nB1 = {0,0}, dA1 = {0,0}, dB1 = {0,0};   // j1

  auto body = [&](v2f g, const v2f& rv, const v2f& ny, v2f& nacc, v2f& dacc) {
    v2f d = __builtin_elementwise_fma(g, rv, ny);   // v_pk_fma_f32 (td from SGPR)
    v2f q = d * d;                                  // v_pk_mul_f32
    v2f p;
    p.x = EXP2(-q.x);                               // v_exp_f32, neg input mod
    p.y = EXP2(-q.y);
    dacc += p;                                      // v_pk_add_f32
    nacc = __builtin_elementwise_fma(p, g, nacc);   // v_pk_fma_f32 (td from SGPR)
  };

  if (lim == CH) {
    #pragma unroll 2
    for (int i = 0; i < CH; i += 8) {
      v8f f = *(const v8f*)(tp + i);     // uniform addr -> s_load_dwordx8
      v2f g0 = {f[0], f[1]}, g1 = {f[2], f[3]};
      v2f g2 = {f[4], f[5]}, g3 = {f[6], f[7]};
      body(g0, rv0, ny0, nA0, dA0);
      body(g1, rv0, ny0, nB0, dB0);
      body(g2, rv0, ny0, nA0, dA0);
      body(g3, rv0, ny0, nB0, dB0);
      body(g0, rv1, ny1, nA1, dA1);
      body(g1, rv1, ny1, nB1, dB1);
      body(g2, rv1, ny1, nA1, dA1);
      body(g3, rv1, ny1, nB1, dB1);
    }
  } else {
    for (int i = 0; i < CH; i += 8) {
      v8f f;
      #pragma unroll
      for (int k = 0; k < 8; ++k) f[k] = (i + k < lim) ? tp[i + k] : 1e30f;
      v2f g0 = {f[0], f[1]}, g1 = {f[2], f[3]};
      v2f g2 = {f[4], f[5]}, g3 = {f[6], f[7]};
      body(g0, rv0, ny0, nA0, dA0);
      body(g1, rv0, ny0, nB0, dB0);
      body(g2, rv0, ny0, nA0, dA0);
      body(g3, rv0, ny0, nB0, dB0);
      body(g0, rv1, ny1, nA1, dA1);
      body(g1, rv1, ny1, nB1, dB1);
      body(g2, rv1, ny1, nA1, dA1);
      body(g3, rv1, ny1, nB1, dB1);
    }
  }

  v2f nv0 = nA0 + nB0, dv0 = dA0 + dB0;
  v2f nv1 = nA1 + nB1, dv1 = dA1 + dB1;
  float num0 = nv0.x + nv0.y, den0 = dv0.x + dv0.y;
  float num1 = nv1.x + nv1.y, den1 = dv1.x + dv1.y;

  if (ATOMIC) {
    if (j0 < B) { atomicAdd(&ws[j0], num0); atomicAdd(&ws[B + j0], den0); }
    if (j1 < B) { atomicAdd(&ws[j1], num1); atomicAdd(&ws[B + j1], den1); }
  } else {
    if (j0 < B) {
      ws[(size_t)s * B + j0]       = num0;   // num partials: [S][B]
      ws[(size_t)(S + s) * B + j0] = den0;   // den partials: [S][B]
    }
    if (j1 < B) {
      ws[(size_t)s * B + j1]       = num1;
      ws[(size_t)(S + s) * B + j1] = den1;
    }
  }
}

__global__ void gmm_final(const float* __restrict__ x,
                          const float* __restrict__ t,
                          const float* __restrict__ ws,
                          float* __restrict__ out, int B, int S) {
  int j = blockIdx.x * blockDim.x + threadIdx.x;
  if (j >= B) return;
  float num = 0.f, den = 0.f;
  for (int s = 0; s < S; ++s) {
    num += ws[(size_t)s * B + j];
    den += ws[(size_t)(S + s) * B + j];
  }
  float sigma2 = sigma2_of(t[j]);
  float evals = (den == 0.0f) ? 0.0f : (num / den);   // reference's den==0 guard
  out[j] = (evals - x[j]) / sigma2;
}

__global__ void zero_kernel(float* __restrict__ p, int n) {
  int i = blockIdx.x * blockDim.x + threadIdx.x;
  if (i < n) p[i] = 0.0f;
}

extern "C" void kernel_launch(void* const* d_in, const int* in_sizes, int n_in,
                              void* d_out, int out_size, void* d_ws, size_t ws_size,
                              hipStream_t stream) {
  const float* x  = (const float*)d_in[0];
  const float* t  = (const float*)d_in[1];
  const float* td = (const float*)d_in[2];
  float* out = (float*)d_out;
  float* ws  = (float*)d_ws;

  const int B = in_sizes[0];
  const int N = in_sizes[2];

  const int S = (N + CH - 1) / CH;                  // 64 for N=16384
  size_t need = (size_t)2 * S * B * sizeof(float);  // 8 MB

  if (ws_size >= need) {
    dim3 grid((B + JPB - 1) / JPB, S);              // (32, 64) = 2048 blocks
    gmm_partial<false><<<grid, BLK, 0, stream>>>(x, t, td, ws, N, B);
    gmm_final<<<(B + BLK - 1) / BLK, BLK, 0, stream>>>(x, t, ws, out, B, S);
  } else {
    // Fallback: zero + atomic accumulate + final (3 dispatches)
    int nzero = 2 * B;
    zero_kernel<<<(nzero + 255) / 256, 256, 0, stream>>>(ws, nzero);
    dim3 grid((B + JPB - 1) / JPB, S);
    gmm_partial<true><<<grid, BLK, 0, stream>>>(x, t, td, ws, N, B);
    gmm_final<<<(B + BLK - 1) / BLK, BLK, 0, stream>>>(x, t, ws, out, B, 1);
  }
}